// Round 1
// baseline (356.321 us; speedup 1.0000x reference)
//
#include <hip/hip_runtime.h>
#include <hip/hip_bf16.h>

// Problem constants
#define BATCH   2048
#define IN_CH   12
#define UPLAG   2048
#define STEP    4
#define FEAT    512              // UPLAG/STEP
#define DIN     6144             // IN_CH*FEAT
#define HIDDEN  1024
#define OUTPUT  256

typedef __bf16 bf16x8 __attribute__((ext_vector_type(8)));
typedef float  f32x4  __attribute__((ext_vector_type(4)));

__device__ __forceinline__ unsigned short f2bf(float f) {
  unsigned int u = __builtin_bit_cast(unsigned int, f);
  unsigned int r = (u + 0x7fffu + ((u >> 16) & 1u)) >> 16;   // RNE
  return (unsigned short)r;
}

__device__ __forceinline__ float bf2f(unsigned short h) {
  unsigned int u = ((unsigned int)h) << 16;
  return __builtin_bit_cast(float, u);
}

__device__ __forceinline__ void async_copy16(const unsigned short* g, unsigned short* l) {
  __builtin_amdgcn_global_load_lds(
      (const __attribute__((address_space(1))) unsigned int*)g,
      (__attribute__((address_space(3))) unsigned int*)l, 16, 0, 0);
}

// ---------------------------------------------------------------------------
// Kernel 1: per-channel stride-4 conv + bias, cast to bf16.
// ---------------------------------------------------------------------------
__global__ __launch_bounds__(256) void conv_cast_kernel(
    const float* __restrict__ x, const float* __restrict__ W1,
    const float* __restrict__ b1, unsigned short* __restrict__ out)
{
  int gid = blockIdx.x * 256 + threadIdx.x;
  const int total = BATCH * DIN;
  if (gid >= total) return;
  int cf = gid % DIN;            // c*FEAT + f
  int c  = cf >> 9;              // /512
  float4 xv = ((const float4*)x)[gid];
  float4 wv = ((const float4*)W1)[c];
  float v = xv.x * wv.x + xv.y * wv.y + xv.z * wv.z + xv.w * wv.w + b1[c];
  out[gid] = f2bf(v);
}

// ---------------------------------------------------------------------------
// Kernel 2: transpose + cast fp32 [R, Ncol] -> bf16 [Ncol, R]
// ---------------------------------------------------------------------------
__global__ __launch_bounds__(256) void transpose_cast(
    const float* __restrict__ in, unsigned short* __restrict__ out,
    int R, int Ncol)
{
  __shared__ float tile[32][33];
  int bx = blockIdx.x * 32;
  int by = blockIdx.y * 32;
  int tx = threadIdx.x, ty = threadIdx.y;   // (32, 8)
  #pragma unroll
  for (int i = 0; i < 32; i += 8)
    tile[ty + i][tx] = in[(size_t)(by + ty + i) * Ncol + bx + tx];
  __syncthreads();
  #pragma unroll
  for (int i = 0; i < 32; i += 8)
    out[(size_t)(bx + ty + i) * R + by + tx] = f2bf(tile[tx][ty + i]);
}

// ---------------------------------------------------------------------------
// Kernel 3: GEMM1 rewritten as 256x256 tile, BK=64, 8 waves (2Mx4N),
// 4-phase-per-K-tile pipelined schedule with counted vmcnt (T3+T4+T5),
// split-K=8 -> 256 blocks = 1 block/CU.
//
// LDS: per operand 2 dbuf x 2 k-half slots of [256 rows][32 kcols] bf16
// (64-byte rows -> ds_read_b128 bank distribution is uniform, no swizzle
// needed). Refill stream: exactly one half-tile per phase, targeting the
// slot whose last read was the previous phase:
//   phase(t,0): A.other.h1[t+1]   phase(t,1): B.other.h1[t+1]
//   phase(t,2): A.cur.h0  [t+2]   phase(t,3): B.cur.h0  [t+2]
// Every refill has a 5-6 phase landing window; vmcnt(6) per phase +
// barrier ordering guarantees loads issued <= P-5 have landed before any
// wave's phase-P ds_reads. 3-4 half-tiles stay in flight across barriers
// (never vmcnt(0) in the main loop).
//
// XCD swizzle: blockIdx%8 = XCD owns a 2m x 2n quadrant (all 8 k-splits):
// per-XCD working set A 6.3MB + B 6.3MB -> total HBM ~100MB.
// ---------------------------------------------------------------------------
#define SPLITK  8
#define G1_KS   768      // 6144/8
#define G1_NTK  12       // 768/64 K-tiles per block

__global__ __launch_bounds__(512, 2) void gemm1_kernel(
    const unsigned short* __restrict__ A,   // [M,K] bf16
    const unsigned short* __restrict__ BT,  // [N,K] bf16
    unsigned short* __restrict__ Cp,        // [SPLITK, M, N] bf16
    int M, int N, int K)
{
  __shared__ alignas(16) unsigned short As[2][2][256][32];   // 64 KB
  __shared__ alignas(16) unsigned short Bs[2][2][256][32];   // 64 KB

  const int t    = threadIdx.x;      // 0..511
  const int lane = t & 63;
  const int wave = t >> 6;           // 0..7
  const int wr   = wave >> 2;        // 0..1  (M half)
  const int wc   = wave & 3;         // 0..3  (N quarter)
  const int lm   = lane & 15;
  const int hi2  = lane >> 4;        // 0..3

  // block decode: XCD (bid&7) owns a 2m x 2n quadrant, all k-splits
  int bid  = blockIdx.x;
  int xcd  = bid & 7;
  int rest = bid >> 3;               // 0..31
  int ml   = rest & 1;
  int nl   = (rest >> 1) & 1;
  int kz   = rest >> 2;              // 0..7
  int yt   = (xcd >> 1) * 2 + ml;    // m-tile 0..7
  int xt   = (xcd & 1) * 2 + nl;     // n-tile 0..3
  const int m0   = yt * 256;
  const int n0   = xt * 256;
  const int kbeg = kz * G1_KS;

  const unsigned short* Ag = A  + (size_t)m0 * K + kbeg;
  const unsigned short* Bg = BT + (size_t)n0 * K + kbeg;

  // staging geometry: half-tile = 256 rows x 32 kcols bf16 = 16 KB
  // 1024 chunks of 16B; thread t does chunks t and t+512 (LDS linear dest)
  const int row0 = t >> 2;
  const int cb0  = (t & 3) * 8;            // ushort col offset in 32-col slot

  auto stA = [&](int bf, int kh, int tt) {
    unsigned short* l0 = &As[bf][kh][0][0];
    const unsigned short* g = Ag + (size_t)tt * 64 + kh * 32;
    async_copy16(g + (size_t)row0 * K + cb0,          l0 + t * 8);
    async_copy16(g + (size_t)(row0 + 128) * K + cb0,  l0 + (t + 512) * 8);
  };
  auto stB = [&](int bf, int kh, int tt) {
    unsigned short* l0 = &Bs[bf][kh][0][0];
    const unsigned short* g = Bg + (size_t)tt * 64 + kh * 32;
    async_copy16(g + (size_t)row0 * K + cb0,          l0 + t * 8);
    async_copy16(g + (size_t)(row0 + 128) * K + cb0,  l0 + (t + 512) * 8);
  };

  f32x4 acc[8][4];
  #pragma unroll
  for (int i = 0; i < 8; i++)
    #pragma unroll
    for (int j = 0; j < 4; j++) {
      f32x4 z = {0.f, 0.f, 0.f, 0.f};
      acc[i][j] = z;
    }

  // prologue: tile0 fully (4 halves), then tile1's h0 halves (12 loads/thread)
  stA(0, 0, 0); stA(0, 1, 0); stB(0, 0, 0); stB(0, 1, 0);
  stA(1, 0, 1); stB(1, 0, 1);
  asm volatile("s_waitcnt vmcnt(4)" ::: "memory");   // tile0 landed
  __builtin_amdgcn_sched_barrier(0);
  __builtin_amdgcn_s_barrier();
  __builtin_amdgcn_sched_barrier(0);

  for (int tk = 0; tk < G1_NTK; ++tk) {
    const int b   = tk & 1;
    const int tn1 = (tk + 1 < G1_NTK) ? tk + 1 : G1_NTK - 1;  // clamped: tail
    const int tn2 = (tk + 2 < G1_NTK) ? tk + 2 : G1_NTK - 1;  // stages land in
    #pragma unroll                                            // dead slots
    for (int p = 0; p < 4; ++p) {
      const int kk = p >> 1;     // k-half consumed this phase
      const int mp = p & 1;      // m-subtile consumed this phase

      // ds-load register subtile: 8 x ds_read_b128
      bf16x8 af[4], bfr[4];
      #pragma unroll
      for (int i = 0; i < 4; ++i)
        af[i] = *(const bf16x8*)(&As[b][kk][wr * 128 + mp * 64 + i * 16 + lm][hi2 * 8]);
      #pragma unroll
      for (int j = 0; j < 4; ++j)
        bfr[j] = *(const bf16x8*)(&Bs[b][kk][wc * 64 + j * 16 + lm][hi2 * 8]);

      // refill one half-tile (slot last read in previous phase)
      if      (p == 0) stA(1 - b, 1, tn1);
      else if (p == 1) stB(1 - b, 1, tn1);
      else if (p == 2) stA(b,     0, tn2);
      else             stB(b,     0, tn2);

      asm volatile("s_waitcnt vmcnt(6)" ::: "memory");  // counted, never 0
      __builtin_amdgcn_sched_barrier(0);
      __builtin_amdgcn_s_barrier();
      __builtin_amdgcn_sched_barrier(0);

      __builtin_amdgcn_s_setprio(1);
      #pragma unroll
      for (int i = 0; i < 4; ++i)
        #pragma unroll
        for (int j = 0; j < 4; ++j)
          acc[mp * 4 + i][j] = __builtin_amdgcn_mfma_f32_16x16x32_bf16(
              af[i], bfr[j], acc[mp * 4 + i][j], 0, 0, 0);
      __builtin_amdgcn_s_setprio(0);
      __builtin_amdgcn_sched_barrier(0);
      __builtin_amdgcn_s_barrier();
      __builtin_amdgcn_sched_barrier(0);
    }
  }

  // epilogue: bf16 partials. C/D layout: col=lane&15, row=(lane>>4)*4+reg
  unsigned short* Co = Cp + (size_t)kz * M * N;
  const int rbase = (lane >> 4) * 4;
  #pragma unroll
  for (int mi = 0; mi < 8; ++mi)
    #pragma unroll
    for (int j = 0; j < 4; ++j) {
      int col = n0 + wc * 64 + j * 16 + lm;
      #pragma unroll
      for (int r = 0; r < 4; ++r) {
        int row = m0 + wr * 128 + mi * 16 + rbase + r;
        Co[(size_t)row * N + col] = f2bf(acc[mi][j][r]);
      }
    }
}

// ---------------------------------------------------------------------------
// Kernel 4: split-K reduce + bias + ReLU -> H bf16 [M, HIDDEN]
// ---------------------------------------------------------------------------
__global__ __launch_bounds__(256) void reduce_bias_relu(
    const unsigned short* __restrict__ Cp, const float* __restrict__ b2,
    unsigned short* __restrict__ H)
{
  const int MN = BATCH * HIDDEN;
  int i4 = blockIdx.x * 256 + threadIdx.x;        // x4 index
  if (i4 >= MN / 4) return;
  float4 s = {0.f, 0.f, 0.f, 0.f};
  #pragma unroll
  for (int p = 0; p < SPLITK; ++p) {
    ushort4 a = ((const ushort4*)(Cp + (size_t)p * MN))[i4];
    s.x += bf2f(a.x); s.y += bf2f(a.y); s.z += bf2f(a.z); s.w += bf2f(a.w);
  }
  int col = (i4 * 4) & (HIDDEN - 1);
  float4 bb = *(const float4*)(b2 + col);
  ushort4 o;
  o.x = f2bf(fmaxf(s.x + bb.x, 0.f));
  o.y = f2bf(fmaxf(s.y + bb.y, 0.f));
  o.z = f2bf(fmaxf(s.z + bb.z, 0.f));
  o.w = f2bf(fmaxf(s.w + bb.w, 0.f));
  ((ushort4*)H)[i4] = o;
}

// ---------------------------------------------------------------------------
// Kernel 5: GEMM2 split-K=4, bf16 partials.
// ---------------------------------------------------------------------------
#define SPLITK2 4

__global__ __launch_bounds__(256, 2) void gemm2_kernel(
    const unsigned short* __restrict__ A,   // [M, K]
    const unsigned short* __restrict__ BT,  // [N, K]
    unsigned short* __restrict__ Cp)        // [SPLITK2, M, N] bf16
{
  const int M = BATCH, N = OUTPUT, K = HIDDEN;
  __shared__ unsigned short As[64 * 32];   // 4 KB
  __shared__ unsigned short Bs[64 * 32];   // 4 KB
  const int t    = threadIdx.x;
  const int lane = t & 63;
  const int wave = t >> 6;
  const int m0 = blockIdx.y * 64;
  const int n0 = blockIdx.x * 64;
  const int Ks = K / SPLITK2;
  const int kbeg = blockIdx.z * Ks;
  const int wm = (wave >> 1) * 32;
  const int wn = (wave & 1) * 32;
  const int lm = lane & 15;
  const int lk = (lane >> 4) * 8;
  const int row = t >> 2;
  const int kc  = (t & 3) * 8;

  f32x4 acc[2][2];
  #pragma unroll
  for (int i = 0; i < 2; i++)
    #pragma unroll
    for (int j = 0; j < 2; j++) {
      f32x4 z = {0.f, 0.f, 0.f, 0.f};
      acc[i][j] = z;
    }

  const unsigned short* Ag = A  + (size_t)m0 * K + kbeg;
  const unsigned short* Bg = BT + (size_t)n0 * K + kbeg;

  for (int kk = 0; kk < Ks; kk += 32) {
    async_copy16(Ag + (size_t)row * K + kk + kc, As + t * 8);
    async_copy16(Bg + (size_t)row * K + kk + kc, Bs + t * 8);
    __syncthreads();
    bf16x8 af[2], bfr[2];
    #pragma unroll
    for (int i = 0; i < 2; i++)
      af[i] = *(const bf16x8*)(As + (wm + i * 16 + lm) * 32 + lk);
    #pragma unroll
    for (int j = 0; j < 2; j++)
      bfr[j] = *(const bf16x8*)(Bs + (wn + j * 16 + lm) * 32 + lk);
    #pragma unroll
    for (int i = 0; i < 2; i++)
      #pragma unroll
      for (int j = 0; j < 2; j++)
        acc[i][j] = __builtin_amdgcn_mfma_f32_16x16x32_bf16(af[i], bfr[j], acc[i][j], 0, 0, 0);
    __syncthreads();
  }

  unsigned short* Co = Cp + (size_t)blockIdx.z * M * N;
  const int rbase = (lane >> 4) * 4;
  #pragma unroll
  for (int i = 0; i < 2; i++)
    #pragma unroll
    for (int j = 0; j < 2; j++) {
      int col = n0 + wn + j * 16 + lm;
      #pragma unroll
      for (int r = 0; r < 4; r++) {
        int row_o = m0 + wm + i * 16 + rbase + r;
        Co[(size_t)row_o * N + col] = f2bf(acc[i][j][r]);
      }
    }
}

// ---------------------------------------------------------------------------
// Kernel 6: GEMM2 split-K reduce + bias -> out fp32 [M, OUTPUT]
// ---------------------------------------------------------------------------
__global__ __launch_bounds__(256) void reduce2_bias(
    const unsigned short* __restrict__ Cp, const float* __restrict__ b3,
    float* __restrict__ out)
{
  const int MN = BATCH * OUTPUT;
  int i4 = blockIdx.x * 256 + threadIdx.x;
  if (i4 >= MN / 4) return;
  float4 s = {0.f, 0.f, 0.f, 0.f};
  #pragma unroll
  for (int p = 0; p < SPLITK2; ++p) {
    ushort4 a = ((const ushort4*)(Cp + (size_t)p * MN))[i4];
    s.x += bf2f(a.x); s.y += bf2f(a.y); s.z += bf2f(a.z); s.w += bf2f(a.w);
  }
  int col = (i4 * 4) & (OUTPUT - 1);
  float4 bb = *(const float4*)(b3 + col);
  float4 o = {s.x + bb.x, s.y + bb.y, s.z + bb.z, s.w + bb.w};
  ((float4*)out)[i4] = o;
}

// ---------------------------------------------------------------------------
extern "C" void kernel_launch(void* const* d_in, const int* in_sizes, int n_in,
                              void* d_out, int out_size, void* d_ws, size_t ws_size,
                              hipStream_t stream)
{
  const float* x  = (const float*)d_in[0];
  const float* W1 = (const float*)d_in[1];
  const float* b1 = (const float*)d_in[2];
  const float* W2 = (const float*)d_in[3];
  const float* b2 = (const float*)d_in[4];
  const float* W3 = (const float*)d_in[5];
  const float* b3 = (const float*)d_in[6];
  float* out = (float*)d_out;

  char* ws = (char*)d_ws;
  unsigned short* flatA = (unsigned short*)ws; ws += (size_t)BATCH * DIN * 2;        // 25.2 MB
  unsigned short* W2T   = (unsigned short*)ws; ws += (size_t)HIDDEN * DIN * 2;       // 12.6 MB
  unsigned short* W3T   = (unsigned short*)ws; ws += (size_t)OUTPUT * HIDDEN * 2;    // 0.5 MB
  unsigned short* Cpart = (unsigned short*)ws; ws += (size_t)SPLITK * BATCH * HIDDEN * 2;  // 33.6 MB
  unsigned short* H     = (unsigned short*)ws; ws += (size_t)BATCH * HIDDEN * 2;     // 4.2 MB
  unsigned short* Cp2   = (unsigned short*)ws; ws += (size_t)SPLITK2 * BATCH * OUTPUT * 2; // 4.2 MB

  // 1. conv + cast (memory-bound streaming pass over x)
  conv_cast_kernel<<<(BATCH * DIN) / 256, 256, 0, stream>>>(x, W1, b1, flatA);
  // 2. weight transpose-casts
  transpose_cast<<<dim3(HIDDEN / 32, DIN / 32), dim3(32, 8), 0, stream>>>(W2, W2T, DIN, HIDDEN);
  transpose_cast<<<dim3(OUTPUT / 32, HIDDEN / 32), dim3(32, 8), 0, stream>>>(W3, W3T, HIDDEN, OUTPUT);
  // 3. GEMM1: 256 blocks x 512 threads, pipelined 256^2 schedule, split-K=8
  gemm1_kernel<<<256, 512, 0, stream>>>(flatA, W2T, Cpart, BATCH, HIDDEN, DIN);
  // 4. reduce + bias + relu
  reduce_bias_relu<<<(BATCH * HIDDEN / 4) / 256, 256, 0, stream>>>(Cpart, b2, H);
  // 5. GEMM2 split-K=4: grid 4 x 32 x 4 = 512 blocks (2 blocks/CU)
  gemm2_kernel<<<dim3(OUTPUT / 64, BATCH / 64, SPLITK2), 256, 0, stream>>>(H, W3T, Cp2);
  // 6. reduce + bias
  reduce2_bias<<<(BATCH * OUTPUT / 4) / 256, 256, 0, stream>>>(Cp2, b3, out);
}

// Round 2
// 349.227 us; speedup vs baseline: 1.0203x; 1.0203x over previous
//
#include <hip/hip_runtime.h>
#include <hip/hip_bf16.h>

// Problem constants
#define BATCH   2048
#define IN_CH   12
#define UPLAG   2048
#define STEP    4
#define FEAT    512              // UPLAG/STEP
#define DIN     6144             // IN_CH*FEAT
#define HIDDEN  1024
#define OUTPUT  256

typedef __bf16 bf16x8 __attribute__((ext_vector_type(8)));
typedef float  f32x4  __attribute__((ext_vector_type(4)));

__device__ __forceinline__ unsigned short f2bf(float f) {
  unsigned int u = __builtin_bit_cast(unsigned int, f);
  unsigned int r = (u + 0x7fffu + ((u >> 16) & 1u)) >> 16;   // RNE
  return (unsigned short)r;
}

__device__ __forceinline__ float bf2f(unsigned short h) {
  unsigned int u = ((unsigned int)h) << 16;
  return __builtin_bit_cast(float, u);
}

__device__ __forceinline__ void async_copy16(const unsigned short* g, unsigned short* l) {
  __builtin_amdgcn_global_load_lds(
      (const __attribute__((address_space(1))) unsigned int*)g,
      (__attribute__((address_space(3))) unsigned int*)l, 16, 0, 0);
}

// ---------------------------------------------------------------------------
// Kernel 1: per-channel stride-4 conv + bias, cast to bf16.
// ---------------------------------------------------------------------------
__global__ __launch_bounds__(256) void conv_cast_kernel(
    const float* __restrict__ x, const float* __restrict__ W1,
    const float* __restrict__ b1, unsigned short* __restrict__ out)
{
  int gid = blockIdx.x * 256 + threadIdx.x;
  const int total = BATCH * DIN;
  if (gid >= total) return;
  int cf = gid % DIN;            // c*FEAT + f
  int c  = cf >> 9;              // /512
  float4 xv = ((const float4*)x)[gid];
  float4 wv = ((const float4*)W1)[c];
  float v = xv.x * wv.x + xv.y * wv.y + xv.z * wv.z + xv.w * wv.w + b1[c];
  out[gid] = f2bf(v);
}

// ---------------------------------------------------------------------------
// Kernel 2: merged transpose + cast for BOTH weight matrices in one launch.
// W2 [6144,1024] -> W2T [1024,6144]: 32x192 = 6144 tile-blocks
// W3 [1024,256]  -> W3T [256,1024]:   8x32  =  256 tile-blocks
// ---------------------------------------------------------------------------
__global__ __launch_bounds__(256) void transpose_cast_both(
    const float* __restrict__ W2, unsigned short* __restrict__ W2T,
    const float* __restrict__ W3, unsigned short* __restrict__ W3T)
{
  __shared__ float tile[32][33];
  int b = blockIdx.x;
  const float* in;
  unsigned short* out;
  int R, Ncol, bx, by;
  if (b < 6144) {
    in = W2; out = W2T; R = DIN; Ncol = HIDDEN;
    bx = (b & 31) * 32; by = (b >> 5) * 32;
  } else {
    int bb = b - 6144;
    in = W3; out = W3T; R = HIDDEN; Ncol = OUTPUT;
    bx = (bb & 7) * 32; by = (bb >> 3) * 32;
  }
  int tx = threadIdx.x, ty = threadIdx.y;   // (32, 8)
  #pragma unroll
  for (int i = 0; i < 32; i += 8)
    tile[ty + i][tx] = in[(size_t)(by + ty + i) * Ncol + bx + tx];
  __syncthreads();
  #pragma unroll
  for (int i = 0; i < 32; i += 8)
    out[(size_t)(bx + ty + i) * R + by + tx] = f2bf(tile[tx][ty + i]);
}

// ---------------------------------------------------------------------------
// Kernel 3: GEMM1, split-K=6, XCD-locality swizzle, bf16 partials.
// (proven m97-structure configuration: 128x128 tile, BK=32, 768 blocks,
//  3 blocks/CU)
// ---------------------------------------------------------------------------
#define G1_BM 128
#define G1_BN 128
#define G1_BK 32
#define SPLITK 6

__global__ __launch_bounds__(256, 2) void gemm1_kernel(
    const unsigned short* __restrict__ A,   // [M,K]
    const unsigned short* __restrict__ BT,  // [N,K]
    unsigned short* __restrict__ Cp,        // [SPLITK, M, N] bf16
    int M, int N, int K)
{
  __shared__ unsigned short As[G1_BM * G1_BK];   // 8 KB
  __shared__ unsigned short Bs[G1_BN * G1_BK];   // 8 KB
  const int t    = threadIdx.x;
  const int lane = t & 63;
  const int wave = t >> 6;

  // swizzle decode: b = ((z*2+ylow)*8 + x)*8 + xcdg ;  y = xcdg*2 + ylow
  int b    = blockIdx.x;
  int xcdg = b & 7;
  int rest = b >> 3;          // 0..95
  int xt   = rest & 7;        // n-tile 0..7
  int zz   = rest >> 3;       // 0..11
  int zt   = zz >> 1;         // k-slice 0..5
  int yt   = (xcdg << 1) | (zz & 1);  // m-tile 0..15

  const int m0 = yt * G1_BM;
  const int n0 = xt * G1_BN;
  const int Ks = K / SPLITK;
  const int kbeg = zt * Ks;

  const int wm = (wave >> 1) * 64;
  const int wn = (wave & 1) * 64;
  const int lm = lane & 15;
  const int lk = (lane >> 4) * 8;

  f32x4 acc[4][4];
  #pragma unroll
  for (int i = 0; i < 4; i++)
    #pragma unroll
    for (int j = 0; j < 4; j++) {
      f32x4 z = {0.f, 0.f, 0.f, 0.f};
      acc[i][j] = z;
    }

  const unsigned short* Ag = A  + (size_t)m0 * K + kbeg;
  const unsigned short* Bg = BT + (size_t)n0 * K + kbeg;

  for (int kk = 0; kk < Ks; kk += G1_BK) {
    #pragma unroll
    for (int r = 0; r < 2; ++r) {
      int chunk = r * 256 + t;
      int row = chunk >> 2;
      int kc  = (chunk & 3) * 8;
      async_copy16(Ag + (size_t)row * K + kk + kc, As + chunk * 8);
    }
    #pragma unroll
    for (int r = 0; r < 2; ++r) {
      int chunk = r * 256 + t;
      int row = chunk >> 2;
      int kc  = (chunk & 3) * 8;
      async_copy16(Bg + (size_t)row * K + kk + kc, Bs + chunk * 8);
    }
    __syncthreads();

    bf16x8 af[4], bfr[4];
    #pragma unroll
    for (int i = 0; i < 4; i++)
      af[i] = *(const bf16x8*)(As + (wm + i * 16 + lm) * G1_BK + lk);
    #pragma unroll
    for (int j = 0; j < 4; j++)
      bfr[j] = *(const bf16x8*)(Bs + (wn + j * 16 + lm) * G1_BK + lk);
    #pragma unroll
    for (int i = 0; i < 4; i++)
      #pragma unroll
      for (int j = 0; j < 4; j++)
        acc[i][j] = __builtin_amdgcn_mfma_f32_16x16x32_bf16(af[i], bfr[j], acc[i][j], 0, 0, 0);
    __syncthreads();
  }

  // epilogue: bf16 partials. C/D layout: col=lane&15, row=(lane>>4)*4+reg
  unsigned short* Co = Cp + (size_t)zt * M * N;
  const int rbase = (lane >> 4) * 4;
  #pragma unroll
  for (int i = 0; i < 4; i++)
    #pragma unroll
    for (int j = 0; j < 4; j++) {
      int col = n0 + wn + j * 16 + lm;
      #pragma unroll
      for (int r = 0; r < 4; r++) {
        int row = m0 + wm + i * 16 + rbase + r;
        Co[(size_t)row * N + col] = f2bf(acc[i][j][r]);
      }
    }
}

// ---------------------------------------------------------------------------
// Kernel 4: split-K reduce + bias + ReLU -> H bf16 [M, HIDDEN]
// ---------------------------------------------------------------------------
__global__ __launch_bounds__(256) void reduce_bias_relu(
    const unsigned short* __restrict__ Cp, const float* __restrict__ b2,
    unsigned short* __restrict__ H)
{
  const int MN = BATCH * HIDDEN;
  int i4 = blockIdx.x * 256 + threadIdx.x;        // x4 index
  if (i4 >= MN / 4) return;
  float4 s = {0.f, 0.f, 0.f, 0.f};
  #pragma unroll
  for (int p = 0; p < SPLITK; ++p) {
    ushort4 a = ((const ushort4*)(Cp + (size_t)p * MN))[i4];
    s.x += bf2f(a.x); s.y += bf2f(a.y); s.z += bf2f(a.z); s.w += bf2f(a.w);
  }
  int col = (i4 * 4) & (HIDDEN - 1);
  float4 bb = *(const float4*)(b2 + col);
  ushort4 o;
  o.x = f2bf(fmaxf(s.x + bb.x, 0.f));
  o.y = f2bf(fmaxf(s.y + bb.y, 0.f));
  o.z = f2bf(fmaxf(s.z + bb.z, 0.f));
  o.w = f2bf(fmaxf(s.w + bb.w, 0.f));
  ((ushort4*)H)[i4] = o;
}

// ---------------------------------------------------------------------------
// Kernel 5: GEMM2 split-K=4, bf16 partials.
// ---------------------------------------------------------------------------
#define SPLITK2 4

__global__ __launch_bounds__(256, 2) void gemm2_kernel(
    const unsigned short* __restrict__ A,   // [M, K]
    const unsigned short* __restrict__ BT,  // [N, K]
    unsigned short* __restrict__ Cp)        // [SPLITK2, M, N] bf16
{
  const int M = BATCH, N = OUTPUT, K = HIDDEN;
  __shared__ unsigned short As[64 * 32];   // 4 KB
  __shared__ unsigned short Bs[64 * 32];   // 4 KB
  const int t    = threadIdx.x;
  const int lane = t & 63;
  const int wave = t >> 6;
  const int m0 = blockIdx.y * 64;
  const int n0 = blockIdx.x * 64;
  const int Ks = K / SPLITK2;
  const int kbeg = blockIdx.z * Ks;
  const int wm = (wave >> 1) * 32;
  const int wn = (wave & 1) * 32;
  const int lm = lane & 15;
  const int lk = (lane >> 4) * 8;
  const int row = t >> 2;
  const int kc  = (t & 3) * 8;

  f32x4 acc[2][2];
  #pragma unroll
  for (int i = 0; i < 2; i++)
    #pragma unroll
    for (int j = 0; j < 2; j++) {
      f32x4 z = {0.f, 0.f, 0.f, 0.f};
      acc[i][j] = z;
    }

  const unsigned short* Ag = A  + (size_t)m0 * K + kbeg;
  const unsigned short* Bg = BT + (size_t)n0 * K + kbeg;

  for (int kk = 0; kk < Ks; kk += 32) {
    async_copy16(Ag + (size_t)row * K + kk + kc, As + t * 8);
    async_copy16(Bg + (size_t)row * K + kk + kc, Bs + t * 8);
    __syncthreads();
    bf16x8 af[2], bfr[2];
    #pragma unroll
    for (int i = 0; i < 2; i++)
      af[i] = *(const bf16x8*)(As + (wm + i * 16 + lm) * 32 + lk);
    #pragma unroll
    for (int j = 0; j < 2; j++)
      bfr[j] = *(const bf16x8*)(Bs + (wn + j * 16 + lm) * 32 + lk);
    #pragma unroll
    for (int i = 0; i < 2; i++)
      #pragma unroll
      for (int j = 0; j < 2; j++)
        acc[i][j] = __builtin_amdgcn_mfma_f32_16x16x32_bf16(af[i], bfr[j], acc[i][j], 0, 0, 0);
    __syncthreads();
  }

  unsigned short* Co = Cp + (size_t)blockIdx.z * M * N;
  const int rbase = (lane >> 4) * 4;
  #pragma unroll
  for (int i = 0; i < 2; i++)
    #pragma unroll
    for (int j = 0; j < 2; j++) {
      int col = n0 + wn + j * 16 + lm;
      #pragma unroll
      for (int r = 0; r < 4; r++) {
        int row_o = m0 + wm + i * 16 + rbase + r;
        Co[(size_t)row_o * N + col] = f2bf(acc[i][j][r]);
      }
    }
}

// ---------------------------------------------------------------------------
// Kernel 6: GEMM2 split-K reduce + bias -> out fp32 [M, OUTPUT]
// ---------------------------------------------------------------------------
__global__ __launch_bounds__(256) void reduce2_bias(
    const unsigned short* __restrict__ Cp, const float* __restrict__ b3,
    float* __restrict__ out)
{
  const int MN = BATCH * OUTPUT;
  int i4 = blockIdx.x * 256 + threadIdx.x;
  if (i4 >= MN / 4) return;
  float4 s = {0.f, 0.f, 0.f, 0.f};
  #pragma unroll
  for (int p = 0; p < SPLITK2; ++p) {
    ushort4 a = ((const ushort4*)(Cp + (size_t)p * MN))[i4];
    s.x += bf2f(a.x); s.y += bf2f(a.y); s.z += bf2f(a.z); s.w += bf2f(a.w);
  }
  int col = (i4 * 4) & (OUTPUT - 1);
  float4 bb = *(const float4*)(b3 + col);
  float4 o = {s.x + bb.x, s.y + bb.y, s.z + bb.z, s.w + bb.w};
  ((float4*)out)[i4] = o;
}

// ---------------------------------------------------------------------------
extern "C" void kernel_launch(void* const* d_in, const int* in_sizes, int n_in,
                              void* d_out, int out_size, void* d_ws, size_t ws_size,
                              hipStream_t stream)
{
  const float* x  = (const float*)d_in[0];
  const float* W1 = (const float*)d_in[1];
  const float* b1 = (const float*)d_in[2];
  const float* W2 = (const float*)d_in[3];
  const float* b2 = (const float*)d_in[4];
  const float* W3 = (const float*)d_in[5];
  const float* b3 = (const float*)d_in[6];
  float* out = (float*)d_out;

  char* ws = (char*)d_ws;
  unsigned short* flatA = (unsigned short*)ws; ws += (size_t)BATCH * DIN * 2;        // 25.2 MB
  unsigned short* W2T   = (unsigned short*)ws; ws += (size_t)HIDDEN * DIN * 2;       // 12.6 MB
  unsigned short* W3T   = (unsigned short*)ws; ws += (size_t)OUTPUT * HIDDEN * 2;    // 0.5 MB
  unsigned short* Cpart = (unsigned short*)ws; ws += (size_t)SPLITK * BATCH * HIDDEN * 2;  // 25.2 MB
  unsigned short* H     = (unsigned short*)ws; ws += (size_t)BATCH * HIDDEN * 2;     // 4.2 MB
  unsigned short* Cp2   = (unsigned short*)ws; ws += (size_t)SPLITK2 * BATCH * OUTPUT * 2; // 4.2 MB

  // 1. conv + cast (memory-bound streaming pass over x)
  conv_cast_kernel<<<(BATCH * DIN) / 256, 256, 0, stream>>>(x, W1, b1, flatA);
  // 2. merged weight transpose-casts (one launch)
  transpose_cast_both<<<6400, dim3(32, 8), 0, stream>>>(W2, W2T, W3, W3T);
  // 3. GEMM1 split-K=6, XCD swizzle: 768 blocks 1-D (3 blocks/CU)
  gemm1_kernel<<<768, 256, 0, stream>>>(flatA, W2T, Cpart, BATCH, HIDDEN, DIN);
  // 4. reduce + bias + relu
  reduce_bias_relu<<<(BATCH * HIDDEN / 4) / 256, 256, 0, stream>>>(Cpart, b2, H);
  // 5. GEMM2 split-K=4: grid 4 x 32 x 4 = 512 blocks (2 blocks/CU)
  gemm2_kernel<<<dim3(OUTPUT / 64, BATCH / 64, SPLITK2), 256, 0, stream>>>(H, W3T, Cp2);
  // 6. reduce + bias
  reduce2_bias<<<(BATCH * OUTPUT / 4) / 256, 256, 0, stream>>>(Cp2, b3, out);
}

// Round 3
// 348.617 us; speedup vs baseline: 1.0221x; 1.0018x over previous
//
#include <hip/hip_runtime.h>
#include <hip/hip_bf16.h>

// Problem constants
#define BATCH   2048
#define IN_CH   12
#define UPLAG   2048
#define STEP    4
#define FEAT    512              // UPLAG/STEP
#define DIN     6144             // IN_CH*FEAT
#define HIDDEN  1024
#define OUTPUT  256

typedef __bf16 bf16x8 __attribute__((ext_vector_type(8)));
typedef float  f32x4  __attribute__((ext_vector_type(4)));

__device__ __forceinline__ unsigned short f2bf(float f) {
  unsigned int u = __builtin_bit_cast(unsigned int, f);
  unsigned int r = (u + 0x7fffu + ((u >> 16) & 1u)) >> 16;   // RNE
  return (unsigned short)r;
}

__device__ __forceinline__ float bf2f(unsigned short h) {
  unsigned int u = ((unsigned int)h) << 16;
  return __builtin_bit_cast(float, u);
}

__device__ __forceinline__ void async_copy16(const unsigned short* g, unsigned short* l) {
  __builtin_amdgcn_global_load_lds(
      (const __attribute__((address_space(1))) unsigned int*)g,
      (__attribute__((address_space(3))) unsigned int*)l, 16, 0, 0);
}

// ---------------------------------------------------------------------------
// Kernel 1: fused pre-pass — one launch for ALL gemm1 prerequisites:
//   blocks [0, 49152):          per-channel stride-4 conv + bias -> flatA bf16
//   blocks [49152, 49152+6144): W2 [6144,1024] -> W2T [1024,6144] bf16
//   blocks [55296, 55552):      W3 [1024,256]  -> W3T [256,1024]  bf16
// Branch is block-uniform; conv path exits before the transpose barrier.
// ---------------------------------------------------------------------------
#define CONV_BLOCKS 49152        // BATCH*DIN/256
#define W2T_BLOCKS  6144         // (DIN/32)*(HIDDEN/32)
#define W3T_BLOCKS  256          // (HIDDEN/32)*(OUTPUT/32)

__global__ __launch_bounds__(256) void fused_pre_kernel(
    const float* __restrict__ x,  const float* __restrict__ W1,
    const float* __restrict__ b1, unsigned short* __restrict__ flatA,
    const float* __restrict__ W2, unsigned short* __restrict__ W2T,
    const float* __restrict__ W3, unsigned short* __restrict__ W3T)
{
  __shared__ float tile[32][33];
  const int b = blockIdx.x;
  const int t = threadIdx.x;

  if (b < CONV_BLOCKS) {
    int gid = b * 256 + t;
    int cf = gid % DIN;            // c*FEAT + f
    int c  = cf >> 9;              // /512
    float4 xv = ((const float4*)x)[gid];
    float4 wv = ((const float4*)W1)[c];
    float v = xv.x * wv.x + xv.y * wv.y + xv.z * wv.z + xv.w * wv.w + b1[c];
    flatA[gid] = f2bf(v);
    return;
  }

  int bb = b - CONV_BLOCKS;
  const float* in;
  unsigned short* out;
  int R, Ncol, bx, by;
  if (bb < W2T_BLOCKS) {
    in = W2; out = W2T; R = DIN; Ncol = HIDDEN;
    bx = (bb & 31) * 32; by = (bb >> 5) * 32;
  } else {
    bb -= W2T_BLOCKS;
    in = W3; out = W3T; R = HIDDEN; Ncol = OUTPUT;
    bx = (bb & 7) * 32; by = (bb >> 3) * 32;
  }
  const int tx = t & 31, ty = t >> 5;   // (32, 8)
  #pragma unroll
  for (int i = 0; i < 32; i += 8)
    tile[ty + i][tx] = in[(size_t)(by + ty + i) * Ncol + bx + tx];
  __syncthreads();
  #pragma unroll
  for (int i = 0; i < 32; i += 8)
    out[(size_t)(bx + ty + i) * R + by + tx] = f2bf(tile[tx][ty + i]);
}

// ---------------------------------------------------------------------------
// Kernel 3: GEMM1, split-K=6, XCD-locality swizzle, bf16 partials.
// (proven m97-structure configuration: 128x128 tile, BK=32, 768 blocks,
//  3 blocks/CU)
// ---------------------------------------------------------------------------
#define G1_BM 128
#define G1_BN 128
#define G1_BK 32
#define SPLITK 6

__global__ __launch_bounds__(256, 2) void gemm1_kernel(
    const unsigned short* __restrict__ A,   // [M,K]
    const unsigned short* __restrict__ BT,  // [N,K]
    unsigned short* __restrict__ Cp,        // [SPLITK, M, N] bf16
    int M, int N, int K)
{
  __shared__ unsigned short As[G1_BM * G1_BK];   // 8 KB
  __shared__ unsigned short Bs[G1_BN * G1_BK];   // 8 KB
  const int t    = threadIdx.x;
  const int lane = t & 63;
  const int wave = t >> 6;

  // swizzle decode: b = ((z*2+ylow)*8 + x)*8 + xcdg ;  y = xcdg*2 + ylow
  int b    = blockIdx.x;
  int xcdg = b & 7;
  int rest = b >> 3;          // 0..95
  int xt   = rest & 7;        // n-tile 0..7
  int zz   = rest >> 3;       // 0..11
  int zt   = zz >> 1;         // k-slice 0..5
  int yt   = (xcdg << 1) | (zz & 1);  // m-tile 0..15

  const int m0 = yt * G1_BM;
  const int n0 = xt * G1_BN;
  const int Ks = K / SPLITK;
  const int kbeg = zt * Ks;

  const int wm = (wave >> 1) * 64;
  const int wn = (wave & 1) * 64;
  const int lm = lane & 15;
  const int lk = (lane >> 4) * 8;

  f32x4 acc[4][4];
  #pragma unroll
  for (int i = 0; i < 4; i++)
    #pragma unroll
    for (int j = 0; j < 4; j++) {
      f32x4 z = {0.f, 0.f, 0.f, 0.f};
      acc[i][j] = z;
    }

  const unsigned short* Ag = A  + (size_t)m0 * K + kbeg;
  const unsigned short* Bg = BT + (size_t)n0 * K + kbeg;

  for (int kk = 0; kk < Ks; kk += G1_BK) {
    #pragma unroll
    for (int r = 0; r < 2; ++r) {
      int chunk = r * 256 + t;
      int row = chunk >> 2;
      int kc  = (chunk & 3) * 8;
      async_copy16(Ag + (size_t)row * K + kk + kc, As + chunk * 8);
    }
    #pragma unroll
    for (int r = 0; r < 2; ++r) {
      int chunk = r * 256 + t;
      int row = chunk >> 2;
      int kc  = (chunk & 3) * 8;
      async_copy16(Bg + (size_t)row * K + kk + kc, Bs + chunk * 8);
    }
    __syncthreads();

    bf16x8 af[4], bfr[4];
    #pragma unroll
    for (int i = 0; i < 4; i++)
      af[i] = *(const bf16x8*)(As + (wm + i * 16 + lm) * G1_BK + lk);
    #pragma unroll
    for (int j = 0; j < 4; j++)
      bfr[j] = *(const bf16x8*)(Bs + (wn + j * 16 + lm) * G1_BK + lk);
    #pragma unroll
    for (int i = 0; i < 4; i++)
      #pragma unroll
      for (int j = 0; j < 4; j++)
        acc[i][j] = __builtin_amdgcn_mfma_f32_16x16x32_bf16(af[i], bfr[j], acc[i][j], 0, 0, 0);
    __syncthreads();
  }

  // epilogue: bf16 partials. C/D layout: col=lane&15, row=(lane>>4)*4+reg
  unsigned short* Co = Cp + (size_t)zt * M * N;
  const int rbase = (lane >> 4) * 4;
  #pragma unroll
  for (int i = 0; i < 4; i++)
    #pragma unroll
    for (int j = 0; j < 4; j++) {
      int col = n0 + wn + j * 16 + lm;
      #pragma unroll
      for (int r = 0; r < 4; r++) {
        int row = m0 + wm + i * 16 + rbase + r;
        Co[(size_t)row * N + col] = f2bf(acc[i][j][r]);
      }
    }
}

// ---------------------------------------------------------------------------
// Kernel 4: split-K reduce + bias + ReLU -> H bf16 [M, HIDDEN]
// ---------------------------------------------------------------------------
__global__ __launch_bounds__(256) void reduce_bias_relu(
    const unsigned short* __restrict__ Cp, const float* __restrict__ b2,
    unsigned short* __restrict__ H)
{
  const int MN = BATCH * HIDDEN;
  int i4 = blockIdx.x * 256 + threadIdx.x;        // x4 index
  if (i4 >= MN / 4) return;
  float4 s = {0.f, 0.f, 0.f, 0.f};
  #pragma unroll
  for (int p = 0; p < SPLITK; ++p) {
    ushort4 a = ((const ushort4*)(Cp + (size_t)p * MN))[i4];
    s.x += bf2f(a.x); s.y += bf2f(a.y); s.z += bf2f(a.z); s.w += bf2f(a.w);
  }
  int col = (i4 * 4) & (HIDDEN - 1);
  float4 bb = *(const float4*)(b2 + col);
  ushort4 o;
  o.x = f2bf(fmaxf(s.x + bb.x, 0.f));
  o.y = f2bf(fmaxf(s.y + bb.y, 0.f));
  o.z = f2bf(fmaxf(s.z + bb.z, 0.f));
  o.w = f2bf(fmaxf(s.w + bb.w, 0.f));
  ((ushort4*)H)[i4] = o;
}

// ---------------------------------------------------------------------------
// Kernel 5: GEMM2 split-K=4, bf16 partials.
// ---------------------------------------------------------------------------
#define SPLITK2 4

__global__ __launch_bounds__(256, 2) void gemm2_kernel(
    const unsigned short* __restrict__ A,   // [M, K]
    const unsigned short* __restrict__ BT,  // [N, K]
    unsigned short* __restrict__ Cp)        // [SPLITK2, M, N] bf16
{
  const int M = BATCH, N = OUTPUT, K = HIDDEN;
  __shared__ unsigned short As[64 * 32];   // 4 KB
  __shared__ unsigned short Bs[64 * 32];   // 4 KB
  const int t    = threadIdx.x;
  const int lane = t & 63;
  const int wave = t >> 6;
  const int m0 = blockIdx.y * 64;
  const int n0 = blockIdx.x * 64;
  const int Ks = K / SPLITK2;
  const int kbeg = blockIdx.z * Ks;
  const int wm = (wave >> 1) * 32;
  const int wn = (wave & 1) * 32;
  const int lm = lane & 15;
  const int lk = (lane >> 4) * 8;
  const int row = t >> 2;
  const int kc  = (t & 3) * 8;

  f32x4 acc[2][2];
  #pragma unroll
  for (int i = 0; i < 2; i++)
    #pragma unroll
    for (int j = 0; j < 2; j++) {
      f32x4 z = {0.f, 0.f, 0.f, 0.f};
      acc[i][j] = z;
    }

  const unsigned short* Ag = A  + (size_t)m0 * K + kbeg;
  const unsigned short* Bg = BT + (size_t)n0 * K + kbeg;

  for (int kk = 0; kk < Ks; kk += 32) {
    async_copy16(Ag + (size_t)row * K + kk + kc, As + t * 8);
    async_copy16(Bg + (size_t)row * K + kk + kc, Bs + t * 8);
    __syncthreads();
    bf16x8 af[2], bfr[2];
    #pragma unroll
    for (int i = 0; i < 2; i++)
      af[i] = *(const bf16x8*)(As + (wm + i * 16 + lm) * 32 + lk);
    #pragma unroll
    for (int j = 0; j < 2; j++)
      bfr[j] = *(const bf16x8*)(Bs + (wn + j * 16 + lm) * 32 + lk);
    #pragma unroll
    for (int i = 0; i < 2; i++)
      #pragma unroll
      for (int j = 0; j < 2; j++)
        acc[i][j] = __builtin_amdgcn_mfma_f32_16x16x32_bf16(af[i], bfr[j], acc[i][j], 0, 0, 0);
    __syncthreads();
  }

  unsigned short* Co = Cp + (size_t)blockIdx.z * M * N;
  const int rbase = (lane >> 4) * 4;
  #pragma unroll
  for (int i = 0; i < 2; i++)
    #pragma unroll
    for (int j = 0; j < 2; j++) {
      int col = n0 + wn + j * 16 + lm;
      #pragma unroll
      for (int r = 0; r < 4; r++) {
        int row_o = m0 + wm + i * 16 + rbase + r;
        Co[(size_t)row_o * N + col] = f2bf(acc[i][j][r]);
      }
    }
}

// ---------------------------------------------------------------------------
// Kernel 6: GEMM2 split-K reduce + bias -> out fp32 [M, OUTPUT]
// ---------------------------------------------------------------------------
__global__ __launch_bounds__(256) void reduce2_bias(
    const unsigned short* __restrict__ Cp, const float* __restrict__ b3,
    float* __restrict__ out)
{
  const int MN = BATCH * OUTPUT;
  int i4 = blockIdx.x * 256 + threadIdx.x;
  if (i4 >= MN / 4) return;
  float4 s = {0.f, 0.f, 0.f, 0.f};
  #pragma unroll
  for (int p = 0; p < SPLITK2; ++p) {
    ushort4 a = ((const ushort4*)(Cp + (size_t)p * MN))[i4];
    s.x += bf2f(a.x); s.y += bf2f(a.y); s.z += bf2f(a.z); s.w += bf2f(a.w);
  }
  int col = (i4 * 4) & (OUTPUT - 1);
  float4 bb = *(const float4*)(b3 + col);
  float4 o = {s.x + bb.x, s.y + bb.y, s.z + bb.z, s.w + bb.w};
  ((float4*)out)[i4] = o;
}

// ---------------------------------------------------------------------------
extern "C" void kernel_launch(void* const* d_in, const int* in_sizes, int n_in,
                              void* d_out, int out_size, void* d_ws, size_t ws_size,
                              hipStream_t stream)
{
  const float* x  = (const float*)d_in[0];
  const float* W1 = (const float*)d_in[1];
  const float* b1 = (const float*)d_in[2];
  const float* W2 = (const float*)d_in[3];
  const float* b2 = (const float*)d_in[4];
  const float* W3 = (const float*)d_in[5];
  const float* b3 = (const float*)d_in[6];
  float* out = (float*)d_out;

  char* ws = (char*)d_ws;
  unsigned short* flatA = (unsigned short*)ws; ws += (size_t)BATCH * DIN * 2;        // 25.2 MB
  unsigned short* W2T   = (unsigned short*)ws; ws += (size_t)HIDDEN * DIN * 2;       // 12.6 MB
  unsigned short* W3T   = (unsigned short*)ws; ws += (size_t)OUTPUT * HIDDEN * 2;    // 0.5 MB
  unsigned short* Cpart = (unsigned short*)ws; ws += (size_t)SPLITK * BATCH * HIDDEN * 2;  // 25.2 MB
  unsigned short* H     = (unsigned short*)ws; ws += (size_t)BATCH * HIDDEN * 2;     // 4.2 MB
  unsigned short* Cp2   = (unsigned short*)ws; ws += (size_t)SPLITK2 * BATCH * OUTPUT * 2; // 4.2 MB

  // 1. fused pre-pass: conv+cast AND both weight transpose-casts, one launch
  fused_pre_kernel<<<CONV_BLOCKS + W2T_BLOCKS + W3T_BLOCKS, 256, 0, stream>>>(
      x, W1, b1, flatA, W2, W2T, W3, W3T);
  // 2. GEMM1 split-K=6, XCD swizzle: 768 blocks 1-D (3 blocks/CU)
  gemm1_kernel<<<768, 256, 0, stream>>>(flatA, W2T, Cpart, BATCH, HIDDEN, DIN);
  // 3. reduce + bias + relu
  reduce_bias_relu<<<(BATCH * HIDDEN / 4) / 256, 256, 0, stream>>>(Cpart, b2, H);
  // 4. GEMM2 split-K=4: grid 4 x 32 x 4 = 512 blocks (2 blocks/CU)
  gemm2_kernel<<<dim3(OUTPUT / 64, BATCH / 64, SPLITK2), 256, 0, stream>>>(H, W3T, Cp2);
  // 5. reduce + bias
  reduce2_bias<<<(BATCH * OUTPUT / 4) / 256, 256, 0, stream>>>(Cp2, b3, out);
}